// Round 2
// baseline (108.428 us; speedup 1.0000x reference)
//
#include <hip/hip_runtime.h>
#include <hip/hip_bf16.h>

// CapsuleLayer dynamic routing, MI355X. fp32 in/out.
// C=10, B=128, N=1152, IN=8, OUT=16, 3 routing iters.
//
// v10 (round 12): G=1, max occupancy. r11 falsified the L3-BW theory:
//   XCD-chunked swizzle (provably shrinks per-XCD W ws 4.7->1.2 MB) moved
//   neither time nor FETCH_SIZE. Diagnosis: latency-bound. LDS 76 KB/block
//   capped us at 2 blocks/CU = 4 waves/SIMD; VGPR_Count=52 means almost no
//   loads in flight per wave -> each wave exposes ~200-500 cyc L2/L3 latency
//   on 72 W-loads, VALUBusy 33%. Fix: G=1 halves ldsP to 36.9 KB ->
//   4 blocks/CU = 8 waves/SIMD (HW max), launch_bounds(512,8) forces
//   VGPR<=64. W cache traffic doubles (755 MB) but we are not cache-BW
//   bound (r11 evidence); swizzle retained so per-XCD W ws stays ~1.2 MB
//   (L2-fit, ~23 us L2-BW floor). Iter-0 sums fused into the priors loop
//   (plain sums of P, logits are all zero) - removes one ldsP sweep.
//
// Structure: G=1, 512 thr, one block per (c,b), 1280 blocks.
//   Lane l: o-quad q=l&3 (owns o=q*4..+3), row-sub r=l>>2; wave w covers rows
//   [w*144,(w+1)*144) in 9 passes of 16. W float4 load = 16 rows x 64 B fully-
//   consumed lines. fp32 accumulation everywhere; only P storage is bf16
//   (absmax 0.0078 vs threshold 0.0172, 2.2x margin). Logit state eliminated:
//   logit = dot(accum-out, P) recomputed per iter. Unnormalized softmax
//   (|logit| <~ 30, fp32-safe). ldsP slots are thread-private: no barrier in
//   the P pipeline (lgkmcnt orders same-thread RAW); ds b64 at 8B lane stride
//   = 2-way bank aliasing = free (m136).

constexpr int C = 10, B = 128, N = 1152, IN = 8, OUT = 16;
constexpr int THREADS = 512;
constexpr int NW = THREADS / 64;          // 8 waves
constexpr int PASSES = N / (NW * 16);     // 9
constexpr int NBLK = C * B;               // 1280
constexpr int NXCD = 8;
constexpr int CHUNK = NBLK / NXCD;        // 160 (1280 % 8 == 0: bijective)

__device__ __forceinline__ unsigned packbf(float a, float b) {
    __hip_bfloat162 h = __float22bfloat162_rn(float2{a, b});  // RNE
    return *(unsigned*)&h;
}
__device__ __forceinline__ float bflo(unsigned u) { return __uint_as_float(u << 16); }
__device__ __forceinline__ float bfhi(unsigned u) { return __uint_as_float(u & 0xffff0000u); }

__global__ __launch_bounds__(THREADS, 8)
void caps_route(const float* __restrict__ Xf, const float* __restrict__ Wf,
                float* __restrict__ Of) {
    // P packed: .x = bf16x2(P0,P1), .y = bf16x2(P2,P3); thread-private slots
    __shared__ uint2 ldsP[PASSES * THREADS];           // 36,864 B
    __shared__ float lds_s[2][NW][OUT];                // parity-buffered wave sums
    __shared__ float lds_sum[2][NW];                   // parity-buffered denoms

    const int t = threadIdx.x;
    const int l = t & 63;
    const int wid = t >> 6;
    const int q = l & 3;        // o-quad: owns o = q*4 .. q*4+3
    const int rsub = l >> 2;    // row-sub within a pass (0..15)

    // XCD-chunked swizzle: physical bid%8 -> XCD (round-robin dispatch).
    // XCD x gets logical [x*160, x*160+160) -> <=2 distinct c resident.
    const int bid = blockIdx.x;
    const int blk = (bid & (NXCD - 1)) * CHUNK + (bid >> 3);
    const int c = blk >> 7;     // 128 consecutive logical blocks share c
    const int b = blk & 127;

    // ---- priors: P[n][o] = sum_i x[b,n,i] * W[c,n,i,o] (fp32 acc, bf16 store)
    // Fused iter-0 routing sums (logits all 0 -> softmax uniform -> plain sum).
    float s40[4] = {0.f, 0.f, 0.f, 0.f};
    #pragma unroll
    for (int p = 0; p < PASSES; ++p) {
        const int n = wid * (16 * PASSES) + p * 16 + rsub;
        const float4* wr = (const float4*)(Wf + (size_t)(c * N + n) * (IN * OUT));
        float4 wv[IN];
        #pragma unroll
        for (int i = 0; i < IN; ++i) wv[i] = wr[i * 4 + q];   // 16 full lines/instr
        const float4* xr = (const float4*)(Xf + (size_t)(b * N + n) * IN);
        const float4 xa = xr[0], xc = xr[1];
        const float xs[8] = { xa.x, xa.y, xa.z, xa.w, xc.x, xc.y, xc.z, xc.w };
        float a0 = 0.f, a1 = 0.f, a2 = 0.f, a3 = 0.f;
        #pragma unroll
        for (int i = 0; i < IN; ++i) {
            a0 = fmaf(xs[i], wv[i].x, a0);
            a1 = fmaf(xs[i], wv[i].y, a1);
            a2 = fmaf(xs[i], wv[i].z, a2);
            a3 = fmaf(xs[i], wv[i].w, a3);
        }
        s40[0] += a0; s40[1] += a1; s40[2] += a2; s40[3] += a3;
        ldsP[p * THREADS + t] = uint2{packbf(a0, a1), packbf(a2, a3)};
    }

    // accumulated output quad-slice (fp32); logit[p] == dot(oa_full16, P[p])
    float oa[4] = {0.f, 0.f, 0.f, 0.f};

    // ---- dynamic routing ----
    for (int it = 0; it < 3; ++it) {
        const int pb = it & 1;
        float s4[4];
        float ssum;
        if (it == 0) {
            ssum = (float)PASSES;
            #pragma unroll
            for (int k = 0; k < 4; ++k) s4[k] = s40[k];
        } else {
            ssum = 0.f;
            #pragma unroll
            for (int k = 0; k < 4; ++k) s4[k] = 0.f;
            #pragma unroll
            for (int p = 0; p < PASSES; ++p) {
                const uint2 u = ldsP[p * THREADS + t];
                const float p0 = bflo(u.x), p1 = bfhi(u.x);
                const float p2 = bflo(u.y), p3 = bfhi(u.y);
                // logit[p] = dot(out_accum, P[p]) via quad butterfly
                float d = oa[0] * p0;
                d = fmaf(oa[1], p1, d);
                d = fmaf(oa[2], p2, d);
                d = fmaf(oa[3], p3, d);
                d += __shfl_xor(d, 1, 64);
                d += __shfl_xor(d, 2, 64);
                const float e = __expf(d);      // replicated across quad
                ssum += e;
                s4[0] = fmaf(e, p0, s4[0]);
                s4[1] = fmaf(e, p1, s4[1]);
                s4[2] = fmaf(e, p2, s4[2]);
                s4[3] = fmaf(e, p3, s4[3]);
            }
        }
        // reduce across the 16 row-subs of the wave (masks 4..32; quad bits
        // 0,1 carry replicas (ssum) / distinct o (s4) -> not summed)
        #pragma unroll
        for (int m = 4; m < 64; m <<= 1) {
            ssum += __shfl_xor(ssum, m, 64);
            #pragma unroll
            for (int k = 0; k < 4; ++k) s4[k] += __shfl_xor(s4[k], m, 64);
        }
        if (l < 4) {  // lane l == quad q: owns o = l*4..l*4+3
            #pragma unroll
            for (int k = 0; k < 4; ++k) lds_s[pb][wid][l * 4 + k] = s4[k];
        }
        if (l == 0) lds_sum[pb][wid] = ssum;
        __syncthreads();

        // all-thread redundant combine + squash (each thread: its own o-quad).
        // lds_s reads are 4 distinct 16B addrs/wave (by q) -> banks 0-15,
        // 16-lane broadcast each, conflict-free. ||s||^2 completed across the
        // quad via shfl_xor 1,2.
        float a0 = 0.f, a1 = 0.f, a2 = 0.f, a3 = 0.f, S = 0.f;
        #pragma unroll
        for (int w = 0; w < NW; ++w) {
            const float4 v = *(const float4*)&lds_s[pb][w][q * 4];
            a0 += v.x; a1 += v.y; a2 += v.z; a3 += v.w;
            S += lds_sum[pb][w];
        }
        const float inv = 1.f / S;
        const float s0 = a0 * inv, s1 = a1 * inv;
        const float s2 = a2 * inv, s3 = a3 * inv;
        float r = s0 * s0 + s1 * s1 + s2 * s2 + s3 * s3;
        r += __shfl_xor(r, 1, 64);
        r += __shfl_xor(r, 2, 64);
        const float sc = r / ((1.f + r) * sqrtf(r + 1e-8f));
        if (it < 2) {
            oa[0] += s0 * sc; oa[1] += s1 * sc;
            oa[2] += s2 * sc; oa[3] += s3 * sc;
        } else if (t < 4) {  // wid==0, rsub==0, q==t: write final outputs
            Of[((size_t)c * B + b) * OUT + q * 4 + 0] = s0 * sc;
            Of[((size_t)c * B + b) * OUT + q * 4 + 1] = s1 * sc;
            Of[((size_t)c * B + b) * OUT + q * 4 + 2] = s2 * sc;
            Of[((size_t)c * B + b) * OUT + q * 4 + 3] = s3 * sc;
        }
    }
}

extern "C" void kernel_launch(void* const* d_in, const int* in_sizes, int n_in,
                              void* d_out, int out_size, void* d_ws, size_t ws_size,
                              hipStream_t stream) {
    const float* X = (const float*)d_in[0];   // [B,N,IN] fp32
    const float* W = (const float*)d_in[1];   // [C,N,IN,OUT] fp32
    float* O = (float*)d_out;                 // [C,B,OUT] fp32
    hipLaunchKernelGGL(caps_route, dim3(NBLK), dim3(THREADS), 0, stream, X, W, O);
}

// Round 3
// 95.212 us; speedup vs baseline: 1.1388x; 1.1388x over previous
//
#include <hip/hip_runtime.h>
#include <hip/hip_bf16.h>

// CapsuleLayer dynamic routing, MI355X. fp32 in/out.
// C=10, B=128, N=1152, IN=8, OUT=16, 3 routing iters.
//
// v11 (round 13): G=1 occupancy WITHOUT spills. v10's launch_bounds(512,8)
//   forced VGPR<=64 against a fully-unrolled priors loop (wv[8] = 32 regs of
//   W live) -> 20.5 MB scratch writes + 12 MB scratch reads, dur up 48->56us.
//   Occupancy theory untested, allocator was over-constrained. v11: plain
//   launch_bounds(512), and the pressure is removed STRUCTURALLY:
//   - #pragma unroll 1 on the priors loop: no cross-pass load hoisting (the
//     register balloon). No register array is dynamically indexed, so no
//     scratch-demotion hazard (that only applied when P was a reg array).
//   - named w0..w7 scalars, 8 loads in flight within a pass (MLP=8); TLP
//     from 8 waves/SIMD covers the rest.
//   Expect ~56 VGPR (v8 evidence) -> VGPR allows 8 waves/SIMD, LDS 38.4 KB
//   allows 4 blocks/CU -> 32 waves/CU, 2x v8's latency hiding.
//
// Structure: G=1, 512 thr, one block per (c,b), 1280 blocks.
//   Lane l: o-quad q=l&3 (owns o=q*4..+3), row-sub r=l>>2; wave w covers rows
//   [w*144,(w+1)*144) in 9 passes of 16. W float4 load = 16 rows x 64 B fully-
//   consumed lines. fp32 accumulation everywhere; only P storage is bf16
//   (absmax 0.0059 vs threshold 0.0172). Logit state eliminated: logit =
//   dot(accum-out, P) recomputed per iter. Unnormalized softmax (|logit| <~30,
//   fp32-safe). ldsP slots thread-private: no barrier in the P pipeline
//   (lgkmcnt orders same-thread RAW); ds b64 at 8B lane stride = 2-way bank
//   aliasing = free (m136). XCD-chunked swizzle keeps per-XCD W ws ~1.2 MB.

constexpr int C = 10, B = 128, N = 1152, IN = 8, OUT = 16;
constexpr int THREADS = 512;
constexpr int NW = THREADS / 64;          // 8 waves
constexpr int PASSES = N / (NW * 16);     // 9
constexpr int NBLK = C * B;               // 1280
constexpr int NXCD = 8;
constexpr int CHUNK = NBLK / NXCD;        // 160 (1280 % 8 == 0: bijective)

__device__ __forceinline__ unsigned packbf(float a, float b) {
    __hip_bfloat162 h = __float22bfloat162_rn(float2{a, b});  // RNE
    return *(unsigned*)&h;
}
__device__ __forceinline__ float bflo(unsigned u) { return __uint_as_float(u << 16); }
__device__ __forceinline__ float bfhi(unsigned u) { return __uint_as_float(u & 0xffff0000u); }

__global__ __launch_bounds__(THREADS)
void caps_route(const float* __restrict__ Xf, const float* __restrict__ Wf,
                float* __restrict__ Of) {
    // P packed: .x = bf16x2(P0,P1), .y = bf16x2(P2,P3); thread-private slots
    __shared__ uint2 ldsP[PASSES * THREADS];           // 36,864 B
    __shared__ float lds_s[2][NW][OUT];                // parity-buffered wave sums
    __shared__ float lds_sum[2][NW];                   // parity-buffered denoms

    const int t = threadIdx.x;
    const int l = t & 63;
    const int wid = t >> 6;
    const int q = l & 3;        // o-quad: owns o = q*4 .. q*4+3
    const int rsub = l >> 2;    // row-sub within a pass (0..15)

    // XCD-chunked swizzle: physical bid%8 -> XCD (round-robin dispatch).
    // XCD x gets logical [x*160, x*160+160) -> <=2 distinct c resident.
    const int bid = blockIdx.x;
    const int blk = (bid & (NXCD - 1)) * CHUNK + (bid >> 3);
    const int c = blk >> 7;     // 128 consecutive logical blocks share c
    const int b = blk & 127;

    // ---- priors: P[n][o] = sum_i x[b,n,i] * W[c,n,i,o] (fp32 acc, bf16 store)
    // Fused iter-0 routing sums (logits all 0 -> softmax uniform -> plain sum).
    // unroll 1: no cross-pass hoisting -> peak VGPR stays ~56 (no spills).
    float s40[4] = {0.f, 0.f, 0.f, 0.f};
    const int nbase = wid * (16 * PASSES) + rsub;
    #pragma unroll 1
    for (int p = 0; p < PASSES; ++p) {
        const int n = nbase + p * 16;
        const float4* wr = (const float4*)(Wf + (size_t)(c * N + n) * (IN * OUT)) + q;
        const float4* xr = (const float4*)(Xf + (size_t)(b * N + n) * IN);
        const float4 xa = xr[0], xc = xr[1];
        const float4 w0 = wr[0],  w1 = wr[4],  w2 = wr[8],  w3 = wr[12];
        const float4 w4 = wr[16], w5 = wr[20], w6 = wr[24], w7 = wr[28];
        float a0 = xa.x * w0.x, a1 = xa.x * w0.y, a2 = xa.x * w0.z, a3 = xa.x * w0.w;
        a0 = fmaf(xa.y, w1.x, a0); a1 = fmaf(xa.y, w1.y, a1);
        a2 = fmaf(xa.y, w1.z, a2); a3 = fmaf(xa.y, w1.w, a3);
        a0 = fmaf(xa.z, w2.x, a0); a1 = fmaf(xa.z, w2.y, a1);
        a2 = fmaf(xa.z, w2.z, a2); a3 = fmaf(xa.z, w2.w, a3);
        a0 = fmaf(xa.w, w3.x, a0); a1 = fmaf(xa.w, w3.y, a1);
        a2 = fmaf(xa.w, w3.z, a2); a3 = fmaf(xa.w, w3.w, a3);
        a0 = fmaf(xc.x, w4.x, a0); a1 = fmaf(xc.x, w4.y, a1);
        a2 = fmaf(xc.x, w4.z, a2); a3 = fmaf(xc.x, w4.w, a3);
        a0 = fmaf(xc.y, w5.x, a0); a1 = fmaf(xc.y, w5.y, a1);
        a2 = fmaf(xc.y, w5.z, a2); a3 = fmaf(xc.y, w5.w, a3);
        a0 = fmaf(xc.z, w6.x, a0); a1 = fmaf(xc.z, w6.y, a1);
        a2 = fmaf(xc.z, w6.z, a2); a3 = fmaf(xc.z, w6.w, a3);
        a0 = fmaf(xc.w, w7.x, a0); a1 = fmaf(xc.w, w7.y, a1);
        a2 = fmaf(xc.w, w7.z, a2); a3 = fmaf(xc.w, w7.w, a3);
        s40[0] += a0; s40[1] += a1; s40[2] += a2; s40[3] += a3;
        ldsP[p * THREADS + t] = uint2{packbf(a0, a1), packbf(a2, a3)};
    }

    // accumulated output quad-slice (fp32); logit[p] == dot(oa_full16, P[p])
    float oa[4] = {0.f, 0.f, 0.f, 0.f};

    // ---- dynamic routing ----
    for (int it = 0; it < 3; ++it) {
        const int pb = it & 1;
        float s4[4];
        float ssum;
        if (it == 0) {
            ssum = (float)PASSES;
            #pragma unroll
            for (int k = 0; k < 4; ++k) s4[k] = s40[k];
        } else {
            ssum = 0.f;
            #pragma unroll
            for (int k = 0; k < 4; ++k) s4[k] = 0.f;
            #pragma unroll
            for (int p = 0; p < PASSES; ++p) {
                const uint2 u = ldsP[p * THREADS + t];
                const float p0 = bflo(u.x), p1 = bfhi(u.x);
                const float p2 = bflo(u.y), p3 = bfhi(u.y);
                // logit[p] = dot(out_accum, P[p]) via quad butterfly
                float d = oa[0] * p0;
                d = fmaf(oa[1], p1, d);
                d = fmaf(oa[2], p2, d);
                d = fmaf(oa[3], p3, d);
                d += __shfl_xor(d, 1, 64);
                d += __shfl_xor(d, 2, 64);
                const float e = __expf(d);      // replicated across quad
                ssum += e;
                s4[0] = fmaf(e, p0, s4[0]);
                s4[1] = fmaf(e, p1, s4[1]);
                s4[2] = fmaf(e, p2, s4[2]);
                s4[3] = fmaf(e, p3, s4[3]);
            }
        }
        // reduce across the 16 row-subs of the wave (masks 4..32; quad bits
        // 0,1 carry replicas (ssum) / distinct o (s4) -> not summed)
        #pragma unroll
        for (int m = 4; m < 64; m <<= 1) {
            ssum += __shfl_xor(ssum, m, 64);
            #pragma unroll
            for (int k = 0; k < 4; ++k) s4[k] += __shfl_xor(s4[k], m, 64);
        }
        if (l < 4) {  // lane l == quad q: owns o = l*4..l*4+3
            #pragma unroll
            for (int k = 0; k < 4; ++k) lds_s[pb][wid][l * 4 + k] = s4[k];
        }
        if (l == 0) lds_sum[pb][wid] = ssum;
        __syncthreads();

        // all-thread redundant combine + squash (each thread: its own o-quad).
        // lds_s reads are 4 distinct 16B addrs/wave (by q) -> banks 0-15,
        // 16-lane broadcast each, conflict-free. ||s||^2 completed across the
        // quad via shfl_xor 1,2.
        float a0 = 0.f, a1 = 0.f, a2 = 0.f, a3 = 0.f, S = 0.f;
        #pragma unroll
        for (int w = 0; w < NW; ++w) {
            const float4 v = *(const float4*)&lds_s[pb][w][q * 4];
            a0 += v.x; a1 += v.y; a2 += v.z; a3 += v.w;
            S += lds_sum[pb][w];
        }
        const float inv = 1.f / S;
        const float s0 = a0 * inv, s1 = a1 * inv;
        const float s2 = a2 * inv, s3 = a3 * inv;
        float r = s0 * s0 + s1 * s1 + s2 * s2 + s3 * s3;
        r += __shfl_xor(r, 1, 64);
        r += __shfl_xor(r, 2, 64);
        const float sc = r / ((1.f + r) * sqrtf(r + 1e-8f));
        if (it < 2) {
            oa[0] += s0 * sc; oa[1] += s1 * sc;
            oa[2] += s2 * sc; oa[3] += s3 * sc;
        } else if (t < 4) {  // wid==0, rsub==0, q==t: write final outputs
            Of[((size_t)c * B + b) * OUT + q * 4 + 0] = s0 * sc;
            Of[((size_t)c * B + b) * OUT + q * 4 + 1] = s1 * sc;
            Of[((size_t)c * B + b) * OUT + q * 4 + 2] = s2 * sc;
            Of[((size_t)c * B + b) * OUT + q * 4 + 3] = s3 * sc;
        }
    }
}

extern "C" void kernel_launch(void* const* d_in, const int* in_sizes, int n_in,
                              void* d_out, int out_size, void* d_ws, size_t ws_size,
                              hipStream_t stream) {
    const float* X = (const float*)d_in[0];   // [B,N,IN] fp32
    const float* W = (const float*)d_in[1];   // [C,N,IN,OUT] fp32
    float* O = (float*)d_out;                 // [C,B,OUT] fp32
    hipLaunchKernelGGL(caps_route, dim3(NBLK), dim3(THREADS), 0, stream, X, W, O);
}